// Round 1
// 1664.874 us; speedup vs baseline: 1.7793x; 1.7793x over previous
//
#include <hip/hip_runtime.h>
#include <hip/hip_fp16.h>

// ForwardWarp via two-phase binning:
//   Pass A: per source pixel, emit 16B record(s) into per-output-tile bins.
//           Slot allocation is WAVE-AGGREGATED: lanes sharing a bin elect a
//           leader that does one atomicAdd for the whole group; members take
//           base+rank -> consecutive slots -> coalesced record stores.
//   Pass B: per tile, accumulate records in LDS, single coalesced out += lds.
// img: (8,3,1024,1024) fp32; flo: (8,2,1024,1024) fp32
// d_out = [imgw (8,3,1024,1024) | onew (8,3,1024,1024)] fp32.

#define NN 8
#define CC 3
#define HH 1024
#define WW 1024
#define HW (HH * WW)
#define NCHW (NN * CC * HW)
#define NBINS (NN * 32 * 32)          // 8192 tiles of 32x32
#define CUR_BYTES (NBINS * 4)

__device__ __forceinline__ unsigned pack2h(float a, float b) {
    __half2 h = __floats2half2_rn(a, b);
    return *reinterpret_cast<unsigned*>(&h);
}
__device__ __forceinline__ float2 unpack2h(unsigned u) {
    __half2 h = *reinterpret_cast<__half2*>(&u);
    return __half22float2(h);
}

// direct global-atomic fallback for one (pixel, tile) when its bin is full
__device__ void apply_fallback(float* imgw, float* onew, int n, int tr, int tc,
                               int ix, int iy, const float wx[2], const float wy[2],
                               float v0, float v1, float v2) {
#pragma unroll
    for (int dx = 0; dx < 2; ++dx) {
        int r = ix + dx;
        if ((unsigned)r >= (unsigned)HH || (r >> 5) != tr) continue;
#pragma unroll
        for (int dy = 0; dy < 2; ++dy) {
            int c = iy + dy;
            if ((unsigned)c >= (unsigned)WW || (c >> 5) != tc) continue;
            float w = wx[dx] * wy[dy];
            long o = (long)(n * CC) * HW + (long)r * WW + c;
            atomicAdd(&imgw[o], v0 * w);
            atomicAdd(&imgw[o + HW], v1 * w);
            atomicAdd(&imgw[o + 2 * HW], v2 * w);
            atomicAdd(&onew[o], w);
            atomicAdd(&onew[o + HW], w);
            atomicAdd(&onew[o + 2 * HW], w);
        }
    }
}

__global__ __launch_bounds__(256) void fwarp_binA(
    const float* __restrict__ img, const float* __restrict__ flo,
    float* __restrict__ imgw, float* __restrict__ onew,
    unsigned* __restrict__ cur, uint4* __restrict__ recs, int CAP)
{
    const int idx = blockIdx.x * 256 + threadIdx.x;   // over N*H*W
    const int lane = threadIdx.x & 63;
    const int wi = idx & (WW - 1);
    const int hi = (idx >> 10) & (HH - 1);
    const int n  = idx >> 20;

    const long pix = (long)hi * WW + wi;
    const long fb = (long)(n * 2) * HW + pix;
    const float yf = flo[fb];         // column shift
    const float xf = flo[fb + HW];    // row shift

    const float x1 = floorf(xf);
    const float y1 = floorf(yf);
    const float fx = xf - x1;
    const float fy = yf - y1;
    const int ix = (int)x1 + hi;      // target row (corner dx=0)
    const int iy = (int)y1 + wi;      // target col (corner dy=0)

    float wx[2], wy[2];
    wx[0] = __expf(-fx * fx);
    wx[1] = __expf(-(fx - 1.0f) * (fx - 1.0f));
    wy[0] = __expf(-fy * fy);
    wy[1] = __expf(-(fy - 1.0f) * (fy - 1.0f));

    const long ib = (long)(n * CC) * HW + pix;
    const float v0 = img[ib];
    const float v1 = img[ib + HW];
    const float v2 = img[ib + 2 * HW];

    // unique tile-rows touched by corner rows {ix, ix+1} ∩ [0,1024)
    int trs[2]; int ntr = 0;
    if ((unsigned)ix < (unsigned)HH) trs[ntr++] = ix >> 5;
    if ((unsigned)(ix + 1) < (unsigned)HH) {
        int t = (ix + 1) >> 5;
        if (ntr == 0 || t != trs[0]) trs[ntr++] = t;
    }
    int tcs[2]; int ntc = 0;
    if ((unsigned)iy < (unsigned)WW) tcs[ntc++] = iy >> 5;
    if ((unsigned)(iy + 1) < (unsigned)WW) {
        int t = (iy + 1) >> 5;
        if (ntc == 0 || t != tcs[0]) tcs[ntc++] = t;
    }

    const unsigned uwx = pack2h(wx[0], wx[1]);
    const unsigned uwy = pack2h(wy[0], wy[1]);
    const unsigned uv01 = pack2h(v0, v1);
    const unsigned uv2 = pack2h(v2, 0.0f) & 0xFFFFu;

    // collect this thread's (bin, loc) list: up to 4 records
    int nrec = 0;
    int binv[4];
    unsigned locv[4];
    for (int i = 0; i < ntr; ++i) {
        for (int j = 0; j < ntc; ++j) {
            const int tr = trs[i], tc = tcs[j];
            const int lr = ix - (tr << 5);          // [-1..31]
            const int lc = iy - (tc << 5);          // [-1..31]
            binv[nrec] = (n << 10) + (tr << 5) + tc;
            locv[nrec] = (unsigned)(lr + 1) | ((unsigned)(lc + 1) << 6);
            ++nrec;
        }
    }

    uint4 rec;
    rec.x = uwx; rec.y = uwy; rec.z = uv01;

    // wave-aggregated slot allocation: one global atomic per distinct bin
    // per wave per round, instead of one per lane.
    for (int k = 0; k < 4; ++k) {
        const bool active = (k < nrec);
        unsigned long long remaining = __ballot(active);
        if (remaining == 0ull) break;               // wave-uniform
        const int mybin = active ? binv[k] : -1;
        while (remaining) {
            const int lead = (int)__builtin_ctzll(remaining);
            const int lead_bin = __shfl(mybin, lead);
            const unsigned long long grp = __ballot(active && (mybin == lead_bin));
            if (active && (mybin == lead_bin)) {
                const unsigned long long lanebit = 1ull << lane;
                const int rank = __popcll(grp & (lanebit - 1ull));
                unsigned base = 0u;
                if (lane == lead)
                    base = atomicAdd(&cur[lead_bin], (unsigned)__popcll(grp));
                base = (unsigned)__shfl((int)base, lead);
                const int slot = (int)base + rank;
                if (slot < CAP) {
                    rec.w = uv2 | (locv[k] << 16);
                    recs[(size_t)lead_bin * CAP + slot] = rec;
                } else {
                    const int tr = (lead_bin >> 5) & 31;
                    const int tc = lead_bin & 31;
                    apply_fallback(imgw, onew, n, tr, tc, ix, iy, wx, wy, v0, v1, v2);
                }
            }
            remaining &= ~grp;
        }
    }
}

__global__ __launch_bounds__(256) void fwarp_binB(
    float* __restrict__ imgw, float* __restrict__ onew,
    const unsigned* __restrict__ cur, const uint4* __restrict__ recs, int CAP)
{
    __shared__ float p0[1024], p1[1024], p2[1024], pw[1024];
    const int bin = blockIdx.x;
    const int tid = threadIdx.x;
    const int n = bin >> 10;
    const int tr = (bin >> 5) & 31;
    const int tc = bin & 31;

#pragma unroll
    for (int i = tid; i < 1024; i += 256) {
        p0[i] = 0.0f; p1[i] = 0.0f; p2[i] = 0.0f; pw[i] = 0.0f;
    }
    __syncthreads();

    const int cnt = min((int)cur[bin], CAP);
    const uint4* base = recs + (size_t)bin * CAP;
    for (int i = tid; i < cnt; i += 256) {
        const uint4 rec = base[i];
        const float2 wx = unpack2h(rec.x);
        const float2 wy = unpack2h(rec.y);
        const float2 v01 = unpack2h(rec.z);
        const float v2 = unpack2h(rec.w & 0xFFFFu).x;
        const unsigned loc = rec.w >> 16;
        const int lr = (int)(loc & 63u) - 1;        // [-1..31]
        const int lc = (int)(loc >> 6) - 1;
        const float wxv[2] = {wx.x, wx.y};
        const float wyv[2] = {wy.x, wy.y};
#pragma unroll
        for (int dx = 0; dx < 2; ++dx) {
            const int r = lr + dx;
            if ((unsigned)r >= 32u) continue;
#pragma unroll
            for (int dy = 0; dy < 2; ++dy) {
                const int c = lc + dy;
                if ((unsigned)c >= 32u) continue;
                const float w = wxv[dx] * wyv[dy];
                const int cell = (r << 5) + c;
                atomicAdd(&p0[cell], v01.x * w);
                atomicAdd(&p1[cell], v01.y * w);
                atomicAdd(&p2[cell], v2 * w);
                atomicAdd(&pw[cell], w);
            }
        }
    }
    __syncthreads();

    // unique-writer coalesced flush: out = out + lds (out holds 0 or rare
    // pass-A fallback atomics; pass A completed before pass B on the stream)
#pragma unroll
    for (int i = tid; i < 1024; i += 256) {
        const int gr = (tr << 5) + (i >> 5);
        const int gc = (tc << 5) + (i & 31);
        const long o = (long)(n * CC) * HW + (long)gr * WW + gc;
        imgw[o]          += p0[i];
        imgw[o + HW]     += p1[i];
        imgw[o + 2 * HW] += p2[i];
        const float w = pw[i];
        onew[o]          += w;
        onew[o + HW]     += w;
        onew[o + 2 * HW] += w;
    }
}

extern "C" void kernel_launch(void* const* d_in, const int* in_sizes, int n_in,
                              void* d_out, int out_size, void* d_ws, size_t ws_size,
                              hipStream_t stream) {
    const float* img = (const float*)d_in[0];
    const float* flo = (const float*)d_in[1];
    float* imgw = (float*)d_out;
    float* onew = imgw + (long)NCHW;

    unsigned* cur = (unsigned*)d_ws;
    uint4* recs = (uint4*)((char*)d_ws + CUR_BYTES);

    // bin capacity from available workspace (mean load ~1090/bin, sigma ~33)
    long cap_l = 0;
    if (ws_size > (size_t)CUR_BYTES)
        cap_l = (long)((ws_size - CUR_BYTES) / ((size_t)NBINS * 16));
    int CAP = (int)(cap_l > 2048 ? 2048 : (cap_l < 0 ? 0 : cap_l));

    hipMemsetAsync(d_out, 0, (size_t)out_size * sizeof(float), stream);
    hipMemsetAsync(cur, 0, CUR_BYTES, stream);

    const int total = NN * HH * WW;            // 8388608
    fwarp_binA<<<total / 256, 256, 0, stream>>>(img, flo, imgw, onew, cur, recs, CAP);
    fwarp_binB<<<NBINS, 256, 0, stream>>>(imgw, onew, cur, recs, CAP);
}

// Round 2
// 1031.997 us; speedup vs baseline: 2.8704x; 1.6133x over previous
//
#include <hip/hip_runtime.h>
#include <hip/hip_fp16.h>

// ForwardWarp via two-phase binning:
//   Pass A: per source pixel, emit 16B record(s) into per-output-tile bins.
//           Slot allocation is BLOCK-AGGREGATED: an LDS table over the 1024
//           (tile_row,tile_col) ids counts this block's records per bin and
//           captures each record's rank; then one global atomicAdd per
//           distinct bin (issued concurrently by many lanes) reserves a
//           contiguous range; records store at base+rank -> coalesced.
//   Pass B: per tile, accumulate records in LDS, single coalesced out += lds.
// img: (8,3,1024,1024) fp32; flo: (8,2,1024,1024) fp32
// d_out = [imgw (8,3,1024,1024) | onew (8,3,1024,1024)] fp32.

#define NN 8
#define CC 3
#define HH 1024
#define WW 1024
#define HW (HH * WW)
#define NCHW (NN * CC * HW)
#define NBINS (NN * 32 * 32)          // 8192 tiles of 32x32
#define CUR_STRIDE 32                 // 1 counter per 128B line (kills false sharing)
#define CUR_BYTES (NBINS * CUR_STRIDE * 4)

__device__ __forceinline__ unsigned pack2h(float a, float b) {
    __half2 h = __floats2half2_rn(a, b);
    return *reinterpret_cast<unsigned*>(&h);
}
__device__ __forceinline__ float2 unpack2h(unsigned u) {
    __half2 h = *reinterpret_cast<__half2*>(&u);
    return __half22float2(h);
}

// direct global-atomic fallback for one (pixel, tile) when its bin is full
__device__ void apply_fallback(float* imgw, float* onew, int n, int tr, int tc,
                               int ix, int iy, const float wx[2], const float wy[2],
                               float v0, float v1, float v2) {
#pragma unroll
    for (int dx = 0; dx < 2; ++dx) {
        int r = ix + dx;
        if ((unsigned)r >= (unsigned)HH || (r >> 5) != tr) continue;
#pragma unroll
        for (int dy = 0; dy < 2; ++dy) {
            int c = iy + dy;
            if ((unsigned)c >= (unsigned)WW || (c >> 5) != tc) continue;
            float w = wx[dx] * wy[dy];
            long o = (long)(n * CC) * HW + (long)r * WW + c;
            atomicAdd(&imgw[o], v0 * w);
            atomicAdd(&imgw[o + HW], v1 * w);
            atomicAdd(&imgw[o + 2 * HW], v2 * w);
            atomicAdd(&onew[o], w);
            atomicAdd(&onew[o + HW], w);
            atomicAdd(&onew[o + 2 * HW], w);
        }
    }
}

__global__ __launch_bounds__(256) void fwarp_binA(
    const float* __restrict__ img, const float* __restrict__ flo,
    float* __restrict__ imgw, float* __restrict__ onew,
    unsigned* __restrict__ cur, uint4* __restrict__ recs, int CAP)
{
    __shared__ unsigned tbl[1024];    // per-(tr,tc): count, then base

    const int tid = threadIdx.x;
    const int idx = blockIdx.x * 256 + tid;   // over N*H*W
    const int wi = idx & (WW - 1);
    const int hi = (idx >> 10) & (HH - 1);
    const int n  = idx >> 20;                 // uniform per block

#pragma unroll
    for (int i = tid; i < 1024; i += 256) tbl[i] = 0u;

    const long pix = (long)hi * WW + wi;
    const long fb = (long)(n * 2) * HW + pix;
    const float yf = flo[fb];         // column shift
    const float xf = flo[fb + HW];    // row shift

    const float x1 = floorf(xf);
    const float y1 = floorf(yf);
    const float fx = xf - x1;
    const float fy = yf - y1;
    const int ix = (int)x1 + hi;      // target row (corner dx=0)
    const int iy = (int)y1 + wi;      // target col (corner dy=0)

    float wx[2], wy[2];
    wx[0] = __expf(-fx * fx);
    wx[1] = __expf(-(fx - 1.0f) * (fx - 1.0f));
    wy[0] = __expf(-fy * fy);
    wy[1] = __expf(-(fy - 1.0f) * (fy - 1.0f));

    const long ib = (long)(n * CC) * HW + pix;
    const float v0 = img[ib];
    const float v1 = img[ib + HW];
    const float v2 = img[ib + 2 * HW];

    // unique tile-rows touched by corner rows {ix, ix+1} ∩ [0,1024)
    int trs[2]; int ntr = 0;
    if ((unsigned)ix < (unsigned)HH) trs[ntr++] = ix >> 5;
    if ((unsigned)(ix + 1) < (unsigned)HH) {
        int t = (ix + 1) >> 5;
        if (ntr == 0 || t != trs[0]) trs[ntr++] = t;
    }
    int tcs[2]; int ntc = 0;
    if ((unsigned)iy < (unsigned)WW) tcs[ntc++] = iy >> 5;
    if ((unsigned)(iy + 1) < (unsigned)WW) {
        int t = (iy + 1) >> 5;
        if (ntc == 0 || t != tcs[0]) tcs[ntc++] = t;
    }

    const unsigned uwx = pack2h(wx[0], wx[1]);
    const unsigned uwy = pack2h(wy[0], wy[1]);
    const unsigned uv01 = pack2h(v0, v1);
    const unsigned uv2 = pack2h(v2, 0.0f) & 0xFFFFu;

    // collect this thread's (tile, loc) list: up to 4 records, distinct tiles
    int nrec = 0;
    int tv[4];
    unsigned locv[4];
#pragma unroll
    for (int i = 0; i < 2; ++i) {
        if (i >= ntr) break;
#pragma unroll
        for (int j = 0; j < 2; ++j) {
            if (j >= ntc) break;
            const int tr = trs[i], tc = tcs[j];
            const int lr = ix - (tr << 5);          // [-1..31]
            const int lc = iy - (tc << 5);          // [-1..31]
            tv[nrec] = (tr << 5) + tc;
            locv[nrec] = (unsigned)(lr + 1) | ((unsigned)(lc + 1) << 6);
            ++nrec;
        }
    }

    __syncthreads();   // tbl zeroed

    // phase 1: per-block count + per-record rank via LDS atomics
    unsigned rankv[4];
#pragma unroll
    for (int k = 0; k < 4; ++k)
        if (k < nrec) rankv[k] = atomicAdd(&tbl[tv[k]], 1u);
    __syncthreads();

    // phase 2: reserve global ranges — one atomic per distinct bin, issued
    // concurrently across lanes (4 independent atomics per thread, pipelined)
    unsigned cnts[4];
#pragma unroll
    for (int j = 0; j < 4; ++j) cnts[j] = tbl[tid + j * 256];
#pragma unroll
    for (int j = 0; j < 4; ++j) {
        if (cnts[j] > 0u) {
            const int e = tid + j * 256;
            const int bin = (n << 10) + e;
            tbl[e] = atomicAdd(&cur[(size_t)bin * CUR_STRIDE], cnts[j]);
        }
    }
    __syncthreads();

    // phase 3: store records at base + rank (consecutive per block per bin)
    uint4 rec;
    rec.x = uwx; rec.y = uwy; rec.z = uv01;
#pragma unroll
    for (int k = 0; k < 4; ++k) {
        if (k < nrec) {
            const unsigned slot = tbl[tv[k]] + rankv[k];
            const int bin = (n << 10) + tv[k];
            if (slot < (unsigned)CAP) {
                rec.w = uv2 | (locv[k] << 16);
                recs[(size_t)bin * CAP + slot] = rec;
            } else {
                apply_fallback(imgw, onew, n, tv[k] >> 5, tv[k] & 31,
                               ix, iy, wx, wy, v0, v1, v2);
            }
        }
    }
}

__global__ __launch_bounds__(256) void fwarp_binB(
    float* __restrict__ imgw, float* __restrict__ onew,
    const unsigned* __restrict__ cur, const uint4* __restrict__ recs, int CAP)
{
    __shared__ float p0[1024], p1[1024], p2[1024], pw[1024];
    const int bin = blockIdx.x;
    const int tid = threadIdx.x;
    const int n = bin >> 10;
    const int tr = (bin >> 5) & 31;
    const int tc = bin & 31;

#pragma unroll
    for (int i = tid; i < 1024; i += 256) {
        p0[i] = 0.0f; p1[i] = 0.0f; p2[i] = 0.0f; pw[i] = 0.0f;
    }
    __syncthreads();

    const int cnt = min((int)cur[(size_t)bin * CUR_STRIDE], CAP);
    const uint4* base = recs + (size_t)bin * CAP;
    for (int i = tid; i < cnt; i += 256) {
        const uint4 rec = base[i];
        const float2 wx = unpack2h(rec.x);
        const float2 wy = unpack2h(rec.y);
        const float2 v01 = unpack2h(rec.z);
        const float v2 = unpack2h(rec.w & 0xFFFFu).x;
        const unsigned loc = rec.w >> 16;
        const int lr = (int)(loc & 63u) - 1;        // [-1..31]
        const int lc = (int)(loc >> 6) - 1;
        const float wxv[2] = {wx.x, wx.y};
        const float wyv[2] = {wy.x, wy.y};
#pragma unroll
        for (int dx = 0; dx < 2; ++dx) {
            const int r = lr + dx;
            if ((unsigned)r >= 32u) continue;
#pragma unroll
            for (int dy = 0; dy < 2; ++dy) {
                const int c = lc + dy;
                if ((unsigned)c >= 32u) continue;
                const float w = wxv[dx] * wyv[dy];
                const int cell = (r << 5) + c;
                atomicAdd(&p0[cell], v01.x * w);
                atomicAdd(&p1[cell], v01.y * w);
                atomicAdd(&p2[cell], v2 * w);
                atomicAdd(&pw[cell], w);
            }
        }
    }
    __syncthreads();

    // unique-writer coalesced flush: out = out + lds (out holds 0 or rare
    // pass-A fallback atomics; pass A completed before pass B on the stream)
#pragma unroll
    for (int i = tid; i < 1024; i += 256) {
        const int gr = (tr << 5) + (i >> 5);
        const int gc = (tc << 5) + (i & 31);
        const long o = (long)(n * CC) * HW + (long)gr * WW + gc;
        imgw[o]          += p0[i];
        imgw[o + HW]     += p1[i];
        imgw[o + 2 * HW] += p2[i];
        const float w = pw[i];
        onew[o]          += w;
        onew[o + HW]     += w;
        onew[o + 2 * HW] += w;
    }
}

extern "C" void kernel_launch(void* const* d_in, const int* in_sizes, int n_in,
                              void* d_out, int out_size, void* d_ws, size_t ws_size,
                              hipStream_t stream) {
    const float* img = (const float*)d_in[0];
    const float* flo = (const float*)d_in[1];
    float* imgw = (float*)d_out;
    float* onew = imgw + (long)NCHW;

    unsigned* cur = (unsigned*)d_ws;
    uint4* recs = (uint4*)((char*)d_ws + CUR_BYTES);

    // bin capacity from available workspace (mean load ~1090/bin, sigma ~33)
    long cap_l = 0;
    if (ws_size > (size_t)CUR_BYTES)
        cap_l = (long)((ws_size - CUR_BYTES) / ((size_t)NBINS * 16));
    int CAP = (int)(cap_l > 2048 ? 2048 : (cap_l < 0 ? 0 : cap_l));

    hipMemsetAsync(d_out, 0, (size_t)out_size * sizeof(float), stream);
    hipMemsetAsync(cur, 0, CUR_BYTES, stream);

    const int total = NN * HH * WW;            // 8388608
    fwarp_binA<<<total / 256, 256, 0, stream>>>(img, flo, imgw, onew, cur, recs, CAP);
    fwarp_binB<<<NBINS, 256, 0, stream>>>(imgw, onew, cur, recs, CAP);
}